// Round 10
// baseline (172.774 us; speedup 1.0000x reference)
//
#include <hip/hip_runtime.h>
#include <hip/hip_bf16.h>

#define N_NODES 20000
#define N_EDGES 150000
#define D 512
#define KK 2048          // GEMM K: 3 rel slots (in A) + 1 self slot (from xb)
#define KREL 1536        // A row stride (3 rel slots only)
#define NROWS 20480
#define NTILES_M 320     // 64-row M tiles

typedef __attribute__((ext_vector_type(8))) short bf16x8_t;
typedef __attribute__((ext_vector_type(4))) float f32x4_t;

// ---- helpers ----
__device__ __forceinline__ unsigned short f2bf(float x) {
    unsigned u = __float_as_uint(x);
    unsigned r = u + 0x7fffu + ((u >> 16) & 1u);   // RNE
    return (unsigned short)(r >> 16);
}
__device__ __forceinline__ unsigned pack2(float a, float b) {
    return (unsigned)f2bf(a) | ((unsigned)f2bf(b) << 16);
}
__device__ __forceinline__ float bflo(unsigned u) { return __uint_as_float(u << 16); }
__device__ __forceinline__ float bfhi(unsigned u) { return __uint_as_float(u & 0xffff0000u); }

// ---- fused prep: transpose_B (384 blocks) | conv_x (5000) | count (587) ----
#define TB_BLOCKS 384
#define CX_BLOCKS 5000
#define CNT_BLOCKS 587
__global__ __launch_bounds__(256) void fused_prep(
    const float* __restrict__ W_rel, const float* __restrict__ W_self,
    short* __restrict__ Bt,
    const float* __restrict__ x, short* __restrict__ xb,
    const int* __restrict__ edst, int* __restrict__ hist,
    const int* __restrict__ ntype, int* __restrict__ tcnt) {
    __shared__ float tile[64][65];
    const int b = blockIdx.x;
    if (b < TB_BLOCKS) {
        const int z = b >> 6;                         // 0..5
        const int rem = b & 63;
        const int e0 = (rem & 7) * 64, d0 = (rem >> 3) * 64;
        const float* src = (z < 3) ? (W_rel + (size_t)z * D * D)
                                   : (W_self + (size_t)(z - 3) * D * D);
        const int cbase = (z < 3) ? z * 512 : KREL + (z - 3) * 512;
        const int tx = threadIdx.x & 63, ty = threadIdx.x >> 6;
#pragma unroll
        for (int j = 0; j < 16; ++j) {
            int dl = ty * 16 + j;
            tile[dl][tx] = src[(size_t)(d0 + dl) * D + e0 + tx];
        }
        __syncthreads();
#pragma unroll
        for (int j = 0; j < 16; ++j) {
            int el = ty * 16 + j;
            Bt[(size_t)(e0 + el) * 3072 + cbase + d0 + tx] = (short)f2bf(tile[tx][el]);
        }
    } else if (b < TB_BLOCKS + CX_BLOCKS) {
        int idx = (b - TB_BLOCKS) * 256 + threadIdx.x;   // < 1,280,000
        const float4* s = (const float4*)x + (size_t)idx * 2;
        float4 a = s[0], bb = s[1];
        uint4 pk;
        pk.x = pack2(a.x, a.y);  pk.y = pack2(a.z, a.w);
        pk.z = pack2(bb.x, bb.y); pk.w = pack2(bb.z, bb.w);
        ((uint4*)xb)[idx] = pk;
    } else {
        int i = (b - TB_BLOCKS - CX_BLOCKS) * 256 + threadIdx.x;
        if (i < N_EDGES) atomicAdd(&hist[edst[i]], 1);
        int lane = threadIdx.x & 63;
        int t = (i < N_NODES) ? ntype[i] : 3;
        unsigned long long m0 = __ballot(t == 0), m1 = __ballot(t == 1), m2 = __ballot(t == 2);
        if (lane == 0) {
            if (m0) atomicAdd(&tcnt[0], __popcll(m0));
            if (m1) atomicAdd(&tcnt[1], __popcll(m1));
            if (m2) atomicAdd(&tcnt[2], __popcll(m2));
        }
    }
}

// ---- scan of 20000 edge-bins -> offs/cur; typeoff; rowmap padding marks ----
__global__ __launch_bounds__(1024) void scan_k(const int* __restrict__ hist,
                                               int* __restrict__ offs,
                                               int* __restrict__ cur,
                                               const int* __restrict__ tcnt,
                                               int* __restrict__ typeoff,
                                               int* __restrict__ rowmap) {
    __shared__ int part[1024];
    const int t = threadIdx.x;
    const int base = t * 20;
    int local[20];
    int sum = 0;
#pragma unroll
    for (int i = 0; i < 20; ++i) {
        int b = base + i;
        int v = (b < N_NODES) ? hist[b] : 0;
        local[i] = sum;
        sum += v;
    }
    part[t] = sum;
    __syncthreads();
    for (int off = 1; off < 1024; off <<= 1) {
        int v = part[t];
        int u = (t >= off) ? part[t - off] : 0;
        __syncthreads();
        part[t] = v + u;
        __syncthreads();
    }
    int tbase = (t > 0) ? part[t - 1] : 0;
#pragma unroll
    for (int i = 0; i < 20; ++i) {
        int b = base + i;
        if (b < N_NODES) {
            int o = tbase + local[i];
            offs[b] = o;
            cur[b] = o;
        }
    }
    if (t == 1023) offs[N_NODES] = part[1023];

    int c0 = tcnt[0], c1 = tcnt[1], c2 = tcnt[2];
    int o1 = (c0 + 127) & ~127;
    int o2 = o1 + ((c1 + 127) & ~127);
    int o3 = o2 + ((c2 + 127) & ~127);
    if (t == 0) { typeoff[0] = 0; typeoff[1] = o1; typeoff[2] = o2; typeoff[3] = o3; }
    int p0 = o1 - c0, p1 = o2 - o1 - c1, p2 = o3 - o2 - c2;
    if (t < p0) rowmap[c0 + t] = -1;
    else if (t < p0 + p1) rowmap[o1 + c1 + (t - p0)] = -1;
    else if (t - p0 - p1 < p2) rowmap[o2 + c2 + (t - p0 - p1)] = -1;
}

// ---- node->row assignment (type-grouped) + edge-id scatter (fused) ----
__global__ __launch_bounds__(256) void assign_scatter_k(
    const int* __restrict__ ntype, const int* __restrict__ typeoff,
    int* __restrict__ tcur, int* __restrict__ noderow, int* __restrict__ rowmap,
    const int* __restrict__ esrc, const int* __restrict__ edst,
    const int* __restrict__ etyp, int* __restrict__ cur, int* __restrict__ sorted) {
    int i = blockIdx.x * 256 + threadIdx.x;
    int lane = threadIdx.x & 63;
    bool valid = i < N_NODES;
    int t = valid ? ntype[i] : 3;
    unsigned long long m0 = __ballot(t == 0), m1 = __ballot(t == 1), m2 = __ballot(t == 2);
    unsigned long long below = (lane == 0) ? 0ull : (~0ull >> (64 - lane));
    int b0 = 0, b1 = 0, b2 = 0;
    if (lane == 0) {
        if (m0) b0 = atomicAdd(&tcur[0], __popcll(m0));
        if (m1) b1 = atomicAdd(&tcur[1], __popcll(m1));
        if (m2) b2 = atomicAdd(&tcur[2], __popcll(m2));
    }
    b0 = __shfl(b0, 0); b1 = __shfl(b1, 0); b2 = __shfl(b2, 0);
    if (valid) {
        unsigned long long mk = (t == 0) ? m0 : (t == 1) ? m1 : m2;
        int bs = (t == 0) ? b0 : (t == 1) ? b1 : b2;
        int row = typeoff[t] + bs + __popcll(mk & below);
        noderow[i] = row;
        rowmap[row] = i;
    }
    if (i < N_EDGES) {
        int dst = edst[i];
        int pos = atomicAdd(&cur[dst], 1);
        sorted[pos] = esrc[i] | (etyp[i] << 16);
    }
}

// ---- aggregate: 2 nodes per wave, 4 gathers in flight; linear A writes ----
#define DECL_ACC(P)                                                                   \
    float P##00=0,P##01=0,P##02=0,P##03=0,P##04=0,P##05=0,P##06=0,P##07=0,            \
          P##10=0,P##11=0,P##12=0,P##13=0,P##14=0,P##15=0,P##16=0,P##17=0,            \
          P##20=0,P##21=0,P##22=0,P##23=0,P##24=0,P##25=0,P##26=0,P##27=0;            \
    int P##c0=0, P##c1=0, P##c2=0;

#define ACC_E(P, r, v) {                                                              \
    float f0=bflo(v.x),f1=bfhi(v.x),f2=bflo(v.y),f3=bfhi(v.y);                        \
    float f4=bflo(v.z),f5=bfhi(v.z),f6=bflo(v.w),f7=bfhi(v.w);                        \
    if ((r)==0){P##00+=f0;P##01+=f1;P##02+=f2;P##03+=f3;P##04+=f4;P##05+=f5;P##06+=f6;P##07+=f7;P##c0++;} \
    else if ((r)==1){P##10+=f0;P##11+=f1;P##12+=f2;P##13+=f3;P##14+=f4;P##15+=f5;P##16+=f6;P##17+=f7;P##c1++;} \
    else {P##20+=f0;P##21+=f1;P##22+=f2;P##23+=f3;P##24+=f4;P##25+=f5;P##26+=f6;P##27+=f7;P##c2++;} }

#define STORE_ACC(P, n) {                                                             \
    const int rowid = noderow[n];                                                     \
    short* row = A + (size_t)rowid * KREL;                                            \
    uint4 q;                                                                          \
    q.x=pack2(P##00,P##01); q.y=pack2(P##02,P##03); q.z=pack2(P##04,P##05); q.w=pack2(P##06,P##07); \
    *(uint4*)(row + 0 * D + lane * 8) = q;                                            \
    q.x=pack2(P##10,P##11); q.y=pack2(P##12,P##13); q.z=pack2(P##14,P##15); q.w=pack2(P##16,P##17); \
    *(uint4*)(row + 1 * D + lane * 8) = q;                                            \
    q.x=pack2(P##20,P##21); q.y=pack2(P##22,P##23); q.z=pack2(P##24,P##25); q.w=pack2(P##26,P##27); \
    *(uint4*)(row + 2 * D + lane * 8) = q;                                            \
    if (lane == 0) { cnt[n]=P##c0; cnt[N_NODES+n]=P##c1; cnt[2*N_NODES+n]=P##c2; } }

__global__ __launch_bounds__(256) void aggregate(const short* __restrict__ xb,
                                                 const int* __restrict__ offs,
                                                 const int* __restrict__ sorted,
                                                 const int* __restrict__ noderow,
                                                 short* __restrict__ A,
                                                 int* __restrict__ cnt) {
    const int wid = threadIdx.x >> 6, lane = threadIdx.x & 63;
    const int n0 = (blockIdx.x * 4 + wid) * 2;
    if (n0 >= N_NODES) return;
    const int n1 = n0 + 1;
    const int s0 = offs[n0], e0 = offs[n0 + 1];
    const int s1 = offs[n1], e1 = offs[n1 + 1];
    const int m0 = e0 - s0, m1 = e1 - s1;

    DECL_ACC(a); DECL_ACC(b);

    int pl0 = (lane < m0) ? sorted[s0 + lane] : 0;
    int pl1 = (lane < m1) ? sorted[s1 + lane] : 0;
    const int mm0 = m0 < 64 ? m0 : 64;
    const int mm1 = m1 < 64 ? m1 : 64;
    const int mmax = mm0 > mm1 ? mm0 : mm1;

    for (int i = 0; i < mmax; i += 2) {
        int p00 = __shfl(pl0, i), p01 = __shfl(pl0, i + 1);
        int p10 = __shfl(pl1, i), p11 = __shfl(pl1, i + 1);
        // branch-free gather issue (safe idx 0 when past end) -> 4 loads in flight
        int i00 = (i     < mm0) ? (p00 & 0xffff) : 0;
        int i10 = (i     < mm1) ? (p10 & 0xffff) : 0;
        int i01 = (i + 1 < mm0) ? (p01 & 0xffff) : 0;
        int i11 = (i + 1 < mm1) ? (p11 & 0xffff) : 0;
        uint4 v00 = ((const uint4*)(xb + (size_t)i00 * D))[lane];
        uint4 v10 = ((const uint4*)(xb + (size_t)i10 * D))[lane];
        uint4 v01 = ((const uint4*)(xb + (size_t)i01 * D))[lane];
        uint4 v11 = ((const uint4*)(xb + (size_t)i11 * D))[lane];
        if (i < mm0)     ACC_E(a, p00 >> 16, v00);
        if (i < mm1)     ACC_E(b, p10 >> 16, v10);
        if (i + 1 < mm0) ACC_E(a, p01 >> 16, v01);
        if (i + 1 < mm1) ACC_E(b, p11 >> 16, v11);
    }
    for (int j = 64; j < m0; ++j) {      // overflow (essentially never taken)
        int p = sorted[s0 + j];
        uint4 v = ((const uint4*)(xb + (size_t)(p & 0xffff) * D))[lane];
        ACC_E(a, p >> 16, v);
    }
    for (int j = 64; j < m1; ++j) {
        int p = sorted[s1 + j];
        uint4 v = ((const uint4*)(xb + (size_t)(p & 0xffff) * D))[lane];
        ACC_E(b, p >> 16, v);
    }

    STORE_ACC(a, n0);
    STORE_ACC(b, n1);
}

// ---- GEMM: 64x128, BK=64, single 24KB LDS buffer, T14 register prefetch ----
__global__ __launch_bounds__(256, 4) void gemm_bias_relu(
    const short* __restrict__ A, const short* __restrict__ Bt,
    const short* __restrict__ xb, float* __restrict__ out,
    const int* __restrict__ cnt, const float* __restrict__ b_rel,
    const float* __restrict__ b_self, const int* __restrict__ typeoff,
    const int* __restrict__ rowmap) {
    __shared__ short lA[64 * 64];
    __shared__ short lB[128 * 64];
    const int tid = threadIdx.x;
    const int lane = tid & 63;
    const int wid = tid >> 6;
    const int wm = wid >> 1, wn = wid & 1;
    const int lr = lane & 15, lk = lane >> 4;

    // bijective XCD-chunk swizzle: 1280 blocks, 8 XCDs, 160/XCD; tn-siblings adjacent
    const int lin = blockIdx.x;
    const int mapped = (lin & 7) * 160 + (lin >> 3);
    const int tm = mapped >> 2;
    const int tn = mapped & 3;

    const int o1 = typeoff[1], o2 = typeoff[2], Mtot = typeoff[3];
    const int arow0 = tm * 64;
    if (arow0 >= Mtot) return;
    const int ttile = (arow0 >= o2) ? 2 : (arow0 >= o1) ? 1 : 0;
    const int tsel = ttile * 512;
    const int brow0 = tn * 128;

    // staging precompute: 2 A-frags + 4 B-frags per thread, source-side swizzle
    const int rowA0 = tid >> 3;
    const int rowA1 = rowA0 + 32;
    const int frA0 = (tid & 7) ^ (rowA0 & 7);
    const int frA1 = (tid & 7) ^ (rowA1 & 7);
    int nA0 = rowmap[arow0 + rowA0]; if (nA0 < 0) nA0 = 0;
    int nA1 = rowmap[arow0 + rowA1]; if (nA1 < 0) nA1 = 0;
    const short* aA0 = A + (size_t)(arow0 + rowA0) * KREL + frA0 * 8;
    const short* aA1 = A + (size_t)(arow0 + rowA1) * KREL + frA1 * 8;
    const short* xA0 = xb + (size_t)nA0 * D + frA0 * 8;
    const short* xA1 = xb + (size_t)nA1 * D + frA1 * 8;
    const short* bP0; const short* bP1; const short* bP2; const short* bP3;
    {
        int p0 = tid,        r0 = p0 >> 3, f0 = (p0 & 7) ^ (r0 & 7);
        int p1 = 256 + tid,  r1 = p1 >> 3, f1 = (p1 & 7) ^ (r1 & 7);
        int p2 = 512 + tid,  r2 = p2 >> 3, f2 = (p2 & 7) ^ (r2 & 7);
        int p3 = 768 + tid,  r3 = p3 >> 3, f3 = (p3 & 7) ^ (r3 & 7);
        bP0 = Bt + (size_t)(brow0 + r0) * 3072 + f0 * 8;
        bP1 = Bt + (size_t)(brow0 + r1) * 3072 + f1 * 8;
        bP2 = Bt + (size_t)(brow0 + r2) * 3072 + f2 * 8;
        bP3 = Bt + (size_t)(brow0 + r3) * 3072 + f3 * 8;
    }
    char* const ldsAc = (char*)lA;
    char* const ldsBc = (char*)lB;

    uint4 rA0, rA1, rB0, rB1, rB2, rB3;

#define LOADREGS(kt) {                                                                \
    const int k0s = (kt) * 64;                                                        \
    if (k0s < KREL) {                                                                 \
        rA0 = *(const uint4*)(aA0 + k0s);                                             \
        rA1 = *(const uint4*)(aA1 + k0s);                                             \
    } else {                                                                          \
        rA0 = *(const uint4*)(xA0 + (k0s - KREL));                                    \
        rA1 = *(const uint4*)(xA1 + (k0s - KREL));                                    \
    }                                                                                 \
    const int bk0s = k0s + (k0s >= KREL ? tsel : 0);                                  \
    rB0 = *(const uint4*)(bP0 + bk0s);                                                \
    rB1 = *(const uint4*)(bP1 + bk0s);                                                \
    rB2 = *(const uint4*)(bP2 + bk0s);                                                \
    rB3 = *(const uint4*)(bP3 + bk0s);                                                \
}

#define WRITE_LDS() {                                                                 \
    *(uint4*)(ldsAc + tid * 16)         = rA0;                                        \
    *(uint4*)(ldsAc + (256 + tid) * 16) = rA1;                                        \
    *(uint4*)(ldsBc + tid * 16)         = rB0;                                        \
    *(uint4*)(ldsBc + (256 + tid) * 16) = rB1;                                        \
    *(uint4*)(ldsBc + (512 + tid) * 16) = rB2;                                        \
    *(uint4*)(ldsBc + (768 + tid) * 16) = rB3;                                        \
}

#define COMPUTE() {                                                                   \
    _Pragma("unroll")                                                                 \
    for (int ks = 0; ks < 2; ++ks) {                                                  \
        bf16x8_t af[2], bfr[4];                                                       \
        _Pragma("unroll")                                                             \
        for (int m = 0; m < 2; ++m) {                                                 \
            int row_l = wm * 32 + m * 16 + lr;                                        \
            int pos = (row_l << 3) + ((ks * 4 + lk) ^ (row_l & 7));                   \
            af[m] = *(const bf16x8_t*)&lA[pos << 3];                                  \
        }                                                                             \
        _Pragma("unroll")                                                             \
        for (int n = 0; n < 4; ++n) {                                                 \
            int row_l = wn * 64 + n * 16 + lr;                                        \
            int pos = (row_l << 3) + ((ks * 4 + lk) ^ (row_l & 7));                   \
            bfr[n] = *(const bf16x8_t*)&lB[pos << 3];                                 \
        }                                                                             \
        __builtin_amdgcn_s_setprio(1);                                                \
        _Pragma("unroll")                                                             \
        for (int m = 0; m < 2; ++m)                                                   \
            _Pragma("unroll")                                                         \
            for (int n = 0; n < 4; ++n)                                               \
                acc[m][n] = __builtin_amdgcn_mfma_f32_16x16x32_bf16(                  \
                    af[m], bfr[n], acc[m][n], 0, 0, 0);                               \
        __builtin_amdgcn_s_setprio(0);                                                \
    }                                                                                 \
}

    f32x4_t acc[2][4] = {};

    LOADREGS(0);
    WRITE_LDS();                 // compiler inserts the vmcnt waits for the reg deps
    __syncthreads();
#pragma unroll 1
    for (int kt = 0; kt < 32; ++kt) {
        if (kt + 1 < 32) {
            LOADREGS(kt + 1);    // issue next tile's loads BEFORE compute (T14)
            __builtin_amdgcn_sched_barrier(0);
        }
        COMPUTE();               // covers the load latency
        __syncthreads();         // waves done reading LDS; loads landed by now
        if (kt + 1 < 32) WRITE_LDS();
        __syncthreads();         // fresh tile visible
    }

#pragma unroll
    for (int m = 0; m < 2; ++m) {
#pragma unroll
        for (int q = 0; q < 4; ++q) {
            int rowg = arow0 + wm * 32 + m * 16 + lk * 4 + q;
            int node = rowmap[rowg];
            if (node < 0) continue;
            float c0 = (float)cnt[node];
            float c1 = (float)cnt[N_NODES + node];
            float c2 = (float)cnt[2 * N_NODES + node];
#pragma unroll
            for (int n = 0; n < 4; ++n) {
                int colg = tn * 128 + wn * 64 + n * 16 + lr;
                float v = acc[m][n][q];
                v += c0 * b_rel[colg] + c1 * b_rel[D + colg] + c2 * b_rel[2 * D + colg];
                v += b_self[tsel + colg];
                v = v > 0.f ? v : 0.f;
                out[(size_t)node * D + colg] = v;
            }
        }
    }
}

extern "C" void kernel_launch(void* const* d_in, const int* in_sizes, int n_in,
                              void* d_out, int out_size, void* d_ws, size_t ws_size,
                              hipStream_t stream) {
    const float* x      = (const float*)d_in[0];
    const float* W_rel  = (const float*)d_in[1];
    const float* b_rel  = (const float*)d_in[2];
    const float* W_self = (const float*)d_in[3];
    const float* b_self = (const float*)d_in[4];
    const int* esrc     = (const int*)d_in[5];
    const int* edst     = (const int*)d_in[6];
    const int* etyp     = (const int*)d_in[7];
    const int* ntyp     = (const int*)d_in[8];
    float* out = (float*)d_out;

    char* ws = (char*)d_ws;
    size_t o = 0;
    short* A       = (short*)(ws + o); o += (size_t)NROWS * KREL * 2;    // 62,914,560
    short* Bt      = (short*)(ws + o); o += (size_t)D * 3072 * 2;        // 3,145,728
    short* xb      = (short*)(ws + o); o += (size_t)N_NODES * D * 2;     // 20,480,000
    int*   cnt     = (int*)(ws + o);   o += (size_t)3 * N_NODES * 4;     // 240,000
    int*   offs    = (int*)(ws + o);   o += 80032;
    int*   cur     = (int*)(ws + o);   o += 80000;
    int*   noderow = (int*)(ws + o);   o += 80000;
    int*   rowmap  = (int*)(ws + o);   o += (size_t)NROWS * 4;           // 81,920
    int*   sorted  = (int*)(ws + o);   o += 600000;
    // zero-region (memset): hist + tcnt + tcur + typeoff, contiguous 80048 B
    int*   hist    = (int*)(ws + o);   o += 80000;
    int*   tcnt    = (int*)(ws + o);   o += 16;
    int*   tcur    = (int*)(ws + o);   o += 16;
    int*   typeoff = (int*)(ws + o);   o += 16;

    hipMemsetAsync(hist, 0, 80048, stream);
    fused_prep<<<TB_BLOCKS + CX_BLOCKS + CNT_BLOCKS, 256, 0, stream>>>(
        W_rel, W_self, Bt, x, xb, edst, hist, ntyp, tcnt);
    scan_k<<<1, 1024, 0, stream>>>(hist, offs, cur, tcnt, typeoff, rowmap);
    assign_scatter_k<<<(N_EDGES + 255) / 256, 256, 0, stream>>>(
        ntyp, typeoff, tcur, noderow, rowmap, esrc, edst, etyp, cur, sorted);
    aggregate<<<(N_NODES / 2 + 3) / 4, 256, 0, stream>>>(xb, offs, sorted, noderow, A, cnt);
    gemm_bias_relu<<<NTILES_M * 4, 256, 0, stream>>>(A, Bt, xb, out, cnt, b_rel, b_self,
                                                     typeoff, rowmap);
}